// Round 6
// baseline (209.853 us; speedup 1.0000x reference)
//
#include <hip/hip_runtime.h>

#define BOUND 1e-6f
#define HALF_PI 1.57079632679489662f

// DPP helper: masked/out-of-range lanes receive `oldv` (1.0 = mult identity).
#define UPD_DPP(oldv, srcv, ctrl, rmask)                                        \
  __int_as_float(__builtin_amdgcn_update_dpp(                                   \
      __float_as_int(oldv), __float_as_int(srcv), (ctrl), (rmask), 0xF, false))

// Inclusive multiplicative scan across 64 lanes, pure VALU (validated R2-R5).
__device__ __forceinline__ float wave_incl_prod(float x) {
    x *= UPD_DPP(1.0f, x, 0x111, 0xF);  // row_shr:1
    x *= UPD_DPP(1.0f, x, 0x112, 0xF);  // row_shr:2
    x *= UPD_DPP(1.0f, x, 0x114, 0xF);  // row_shr:4
    x *= UPD_DPP(1.0f, x, 0x118, 0xF);  // row_shr:8
    x *= UPD_DPP(1.0f, x, 0x142, 0xA);  // row_bcast:15 -> rows 1,3
    x *= UPD_DPP(1.0f, x, 0x143, 0xC);  // row_bcast:31 -> rows 2,3
    return x;
}

// Block = 512 threads (8 waves) owns 32 consecutive rows, staged in LDS
// (32 x 257 f32 = 32896 B, 128B-multiple => full-line aligned global stores;
// R5-validated, -15%). THIS ROUND: compute phase uses COLUMN-OWNERSHIP
// (lane l owns cols {l,64+l,128+l,192+l}; R2-validated math) so the LDS
// writes are stride-1 across lanes: dword addr 257*r + l + 64k -> bank
// (r+l)%32 -> 2 lanes/bank = conflict-free, replacing the previous
// stride-4-dword scalar writes (8 banks, 8-way conflict, ~90% LDS pressure).
// out[j]   = radius * prod_{i<j}(sin(a_i)+B) * (cos(a_j)+B),  j < 256
// out[256] = radius * prod_{i<256}(sin(a_i)+B)
__global__ __launch_bounds__(512) void spherize_kernel(
    const float* __restrict__ x,
    const float* __restrict__ p_phiL,
    const float* __restrict__ p_radius,
    const float* __restrict__ p_scaling,
    float* __restrict__ out,
    int n_rows)
{
    __shared__ float lds[32 * 257];   // 32896 B

    const float phi_L   = p_phiL[0];
    const float radius  = p_radius[0];
    const float scaling = p_scaling[0];
    const float amp     = HALF_PI - phi_L;

    const int tid  = threadIdx.x;
    const int lane = tid & 63;
    const int wave = tid >> 6;              // 0..7
    const int row0 = blockIdx.x * 32;       // block's first row
    const int wrow = row0 + wave * 4;       // this wave's first row

    const int nr_blk = min(32, n_rows - row0);        // rows in this block
    const int nr_w   = min(4, max(0, n_rows - wrow)); // rows for this wave

    // ---- load this wave's rows up front: 4 x 256B coalesced dword loads/row
    // (column ownership: lane l loads cols l, 64+l, 128+l, 192+l) ----
    float xv[4][4];
    const float* xb = x + (size_t)wrow * 256 + lane;
    #pragma unroll
    for (int i = 0; i < 4; ++i)
        if (i < nr_w) {
            #pragma unroll
            for (int k = 0; k < 4; ++k)
                xv[i][k] = xb[i * 256 + k * 64];
        }

    // ---- compute rows into LDS (R2-validated segment-scan math) ----
    #pragma unroll
    for (int i = 0; i < 4; ++i) {
        if (i >= nr_w) break;
        float s[4], c[4];
        #pragma unroll
        for (int k = 0; k < 4; ++k) {
            float e  = __expf(-scaling * xv[i][k]);
            float sg = __builtin_amdgcn_rcpf(1.0f + e);
            float a  = fmaf(amp, sg, phi_L);   // a in [phi_L, pi/2)
            s[k] = __sinf(a) + BOUND;          // s in [~0.947, 1+1e-6]
            c[k] = __cosf(a) + BOUND;
        }

        // 4 independent segment scans (ILP), all in VALU
        float incl[4];
        #pragma unroll
        for (int k = 0; k < 4; ++k) incl[k] = wave_incl_prod(s[k]);

        float U = radius;   // radius * product of segments < k
        float* lrow = lds + (wave * 4 + i) * 257 + lane;
        #pragma unroll
        for (int k = 0; k < 4; ++k) {
            // exclusive prefix within segment: incl / s (s >= 0.947, rcp ~1ulp)
            float excl = incl[k] * __builtin_amdgcn_rcpf(s[k]);
            lrow[64 * k] = U * excl * c[k];    // bank (r+l)%32: conflict-free
            float T = __int_as_float(
                __builtin_amdgcn_readlane(__float_as_int(incl[k]), 63));
            U *= T;
        }
        if (lane == 63)
            lrow[256 - 63] = U;                // col 256: radius * full product
    }
    __syncthreads();

    // ---- cooperative aligned full-line store of the block's region ----
    float* obase = out + (size_t)row0 * 257;
    if (nr_blk == 32) {
        // 32*257 = 8224 dwords = 2056 float4s, region 128B-aligned
        const float4* l4 = reinterpret_cast<const float4*>(lds);
        float4*       o4 = reinterpret_cast<float4*>(obase);
        o4[tid]        = l4[tid];
        o4[tid + 512]  = l4[tid + 512];
        o4[tid + 1024] = l4[tid + 1024];
        o4[tid + 1536] = l4[tid + 1536];
        if (tid < 8) o4[tid + 2048] = l4[tid + 2048];
    } else {
        // tail block (not hit for N=524288): safe dword cooperative store
        const int nd = nr_blk * 257;
        for (int i = tid; i < nd; i += 512) obase[i] = lds[i];
    }
}

extern "C" void kernel_launch(void* const* d_in, const int* in_sizes, int n_in,
                              void* d_out, int out_size, void* d_ws, size_t ws_size,
                              hipStream_t stream) {
    // inputs: 0=x [N,256], 1=W_theta, 2=W_phi, 3=b_phi, 4=phi_L, 5=radius, 6=scaling
    const float* x         = (const float*)d_in[0];
    const float* p_phiL    = (const float*)d_in[4];
    const float* p_radius  = (const float*)d_in[5];
    const float* p_scaling = (const float*)d_in[6];
    float* out = (float*)d_out;

    const int n_rows = in_sizes[0] / 256;
    const int blocks = (n_rows + 31) / 32;   // 16384 for N=524288

    spherize_kernel<<<blocks, 512, 0, stream>>>(x, p_phiL, p_radius, p_scaling,
                                                out, n_rows);
}

// Round 7
// 208.143 us; speedup vs baseline: 1.0082x; 1.0082x over previous
//
#include <hip/hip_runtime.h>

#define BOUND 1e-6f
#define HALF_PI 1.57079632679489662f

// DPP helper: masked/out-of-range lanes receive `oldv` (1.0 = mult identity).
#define UPD_DPP(oldv, srcv, ctrl, rmask)                                        \
  __int_as_float(__builtin_amdgcn_update_dpp(                                   \
      __float_as_int(oldv), __float_as_int(srcv), (ctrl), (rmask), 0xF, false))

// Inclusive multiplicative scan across 64 lanes, pure VALU (validated R2-R6).
__device__ __forceinline__ float wave_incl_prod(float x) {
    x *= UPD_DPP(1.0f, x, 0x111, 0xF);  // row_shr:1
    x *= UPD_DPP(1.0f, x, 0x112, 0xF);  // row_shr:2
    x *= UPD_DPP(1.0f, x, 0x114, 0xF);  // row_shr:4
    x *= UPD_DPP(1.0f, x, 0x118, 0xF);  // row_shr:8
    x *= UPD_DPP(1.0f, x, 0x142, 0xA);  // row_bcast:15 -> rows 1,3
    x *= UPD_DPP(1.0f, x, 0x143, 0xC);  // row_bcast:31 -> rows 2,3
    return x;
}

// R6 structure (LDS-staged full-line stores, column ownership) with ONE
// change: sin/cos of the angle replaced by full-rate polynomials in
// u = pi/2 - a = amp * e * sigmoid  (u in (0, 0.325], amp = pi/2 - phi_L):
//   sin(a) = cos(u) = 1 - u^2/2 + u^4/24          (err <= 1.6e-6)
//   cos(a) = sin(u) = u*(1 - u^2/6 + u^4/120)     (err <= 7.5e-8)
// This cuts quarter-rate transcendental ops from 20/row to 12/row (the
// hypothesized residual limiter: trans pipe was ~80-91% busy at roofline
// cadence with hw sin/cos).
// out[j]   = radius * prod_{i<j}(sin(a_i)+B) * (cos(a_j)+B),  j < 256
// out[256] = radius * prod_{i<256}(sin(a_i)+B)
__global__ __launch_bounds__(512) void spherize_kernel(
    const float* __restrict__ x,
    const float* __restrict__ p_phiL,
    const float* __restrict__ p_radius,
    const float* __restrict__ p_scaling,
    float* __restrict__ out,
    int n_rows)
{
    __shared__ float lds[32 * 257];   // 32896 B

    const float phi_L   = p_phiL[0];
    const float radius  = p_radius[0];
    const float scaling = p_scaling[0];
    const float amp     = HALF_PI - phi_L;

    const int tid  = threadIdx.x;
    const int lane = tid & 63;
    const int wave = tid >> 6;              // 0..7
    const int row0 = blockIdx.x * 32;       // block's first row
    const int wrow = row0 + wave * 4;       // this wave's first row

    const int nr_blk = min(32, n_rows - row0);        // rows in this block
    const int nr_w   = min(4, max(0, n_rows - wrow)); // rows for this wave

    // ---- load this wave's rows up front: 4 x 256B coalesced dword loads/row
    // (column ownership: lane l loads cols l, 64+l, 128+l, 192+l) ----
    float xv[4][4];
    const float* xb = x + (size_t)wrow * 256 + lane;
    #pragma unroll
    for (int i = 0; i < 4; ++i)
        if (i < nr_w) {
            #pragma unroll
            for (int k = 0; k < 4; ++k)
                xv[i][k] = xb[i * 256 + k * 64];
        }

    // ---- compute rows into LDS ----
    #pragma unroll
    for (int i = 0; i < 4; ++i) {
        if (i >= nr_w) break;
        float s[4], c[4];
        #pragma unroll
        for (int k = 0; k < 4; ++k) {
            float e  = __expf(-scaling * xv[i][k]);
            float sg = __builtin_amdgcn_rcpf(1.0f + e);
            // u = pi/2 - a = amp*(1-sg) = amp*e*sg  (no cancellation)
            float u  = amp * e * sg;
            float u2 = u * u;
            // sin(a) = cos(u), cos(a) = sin(u): full-rate polys
            float cu = fmaf(u2, fmaf(u2, 4.16666667e-2f, -0.5f), 1.0f);
            float su = u * fmaf(u2, fmaf(u2, 8.33333333e-3f, -1.66666667e-1f), 1.0f);
            s[k] = cu + BOUND;          // s in [~0.947, 1+1e-6]
            c[k] = su + BOUND;
        }

        // 4 independent segment scans (ILP), all in VALU
        float incl[4];
        #pragma unroll
        for (int k = 0; k < 4; ++k) incl[k] = wave_incl_prod(s[k]);

        float U = radius;   // radius * product of segments < k
        float* lrow = lds + (wave * 4 + i) * 257 + lane;
        #pragma unroll
        for (int k = 0; k < 4; ++k) {
            // exclusive prefix within segment: incl / s (s >= 0.947, rcp ~1ulp)
            float excl = incl[k] * __builtin_amdgcn_rcpf(s[k]);
            lrow[64 * k] = U * excl * c[k];    // bank (r+l)%32: conflict-free
            float T = __int_as_float(
                __builtin_amdgcn_readlane(__float_as_int(incl[k]), 63));
            U *= T;
        }
        if (lane == 63)
            lrow[256 - 63] = U;                // col 256: radius * full product
    }
    __syncthreads();

    // ---- cooperative aligned full-line store of the block's region ----
    float* obase = out + (size_t)row0 * 257;
    if (nr_blk == 32) {
        // 32*257 = 8224 dwords = 2056 float4s, region 128B-aligned
        const float4* l4 = reinterpret_cast<const float4*>(lds);
        float4*       o4 = reinterpret_cast<float4*>(obase);
        o4[tid]        = l4[tid];
        o4[tid + 512]  = l4[tid + 512];
        o4[tid + 1024] = l4[tid + 1024];
        o4[tid + 1536] = l4[tid + 1536];
        if (tid < 8) o4[tid + 2048] = l4[tid + 2048];
    } else {
        // tail block (not hit for N=524288): safe dword cooperative store
        const int nd = nr_blk * 257;
        for (int i = tid; i < nd; i += 512) obase[i] = lds[i];
    }
}

extern "C" void kernel_launch(void* const* d_in, const int* in_sizes, int n_in,
                              void* d_out, int out_size, void* d_ws, size_t ws_size,
                              hipStream_t stream) {
    // inputs: 0=x [N,256], 1=W_theta, 2=W_phi, 3=b_phi, 4=phi_L, 5=radius, 6=scaling
    const float* x         = (const float*)d_in[0];
    const float* p_phiL    = (const float*)d_in[4];
    const float* p_radius  = (const float*)d_in[5];
    const float* p_scaling = (const float*)d_in[6];
    float* out = (float*)d_out;

    const int n_rows = in_sizes[0] / 256;
    const int blocks = (n_rows + 31) / 32;   // 16384 for N=524288

    spherize_kernel<<<blocks, 512, 0, stream>>>(x, p_phiL, p_radius, p_scaling,
                                                out, n_rows);
}